// Round 3
// baseline (263.202 us; speedup 1.0000x reference)
//
#include <hip/hip_runtime.h>

#define BB 4
#define TT 2048
#define CC 1024
#define HH 16
#define DD 64
#define WIN 256

typedef __attribute__((ext_vector_type(8))) short short8;
typedef __attribute__((ext_vector_type(4))) float floatx4;
typedef unsigned short u16;

typedef __attribute__((address_space(3))) void lds_void;
typedef const __attribute__((address_space(1))) void g_void;

__device__ __forceinline__ void gl_lds16(const u16* g, u16* l) {
    // async DMA global->LDS, 16B/lane; LDS dst = wave-uniform base + lane*16
    __builtin_amdgcn_global_load_lds((g_void*)g, (lds_void*)l, 16, 0, 0);
}

__device__ __forceinline__ float bf2f(u16 u) {
    union { unsigned int i; float f; } v; v.i = ((unsigned int)u) << 16; return v.f;
}
__device__ __forceinline__ u16 f2bf(float f) {
    union { float f; unsigned int i; } v; v.f = f;
    unsigned int x = v.i;
    x += ((x >> 16) & 1u) + 0x7FFFu;   // round-to-nearest-even
    return (u16)(x >> 16);
}

// ---------------- fp32 -> bf16 conversion (all three arrays, one launch) -----
__global__ void cvt_all(const float* __restrict__ x, const float* __restrict__ qw,
                        const float* __restrict__ pw,
                        u16* __restrict__ xb, u16* __restrict__ wb, u16* __restrict__ pwb) {
    int bid = blockIdx.x;
    const float* src; u16* dst; int off;
    if (bid < 4096)      { src = x;  dst = xb;  off = bid; }
    else if (bid < 5632) { src = qw; dst = wb;  off = bid - 4096; }
    else                 { src = pw; dst = pwb; off = bid - 5632; }
    int i = (off * 256 + (int)threadIdx.x) * 8;
    float4 a = *(const float4*)(src + i);
    float4 b = *(const float4*)(src + i + 4);
    u16 o[8] = { f2bf(a.x), f2bf(a.y), f2bf(a.z), f2bf(a.w),
                 f2bf(b.x), f2bf(b.y), f2bf(b.z), f2bf(b.w) };
    *(uint4*)(dst + i) = *(const uint4*)o;
}

// ============================================================================
// 256x128-tile bf16 GEMM, BK=64, 2-phases-per-K-tile counted-vmcnt schedule.
//   512 threads = 8 waves (4M x 2N); per-wave output 64x64 (acc 4x4).
//   LDS 96KB: lA[2][2][8192] (A k-halves, 256r x 32c), lB[2][2][4096] (128r x 32c).
//   Half = segments of 16 rows x 32 cols (1KB); chunk (row,c) at within-seg
//   (row&15)*64B + (c ^ ((row>>1)&3))*16B -> conflict-free ds_read_b128
//   (measured 0 conflicts in predecessors with identical segment geometry).
//   Phase = { ds-read 8 frags; stage trio (A-half 2 loads + B-half 1 load);
//             vmcnt(6); barrier; setprio1; 16 MFMA; setprio0; barrier }.
//   vmcnt(6) keeps 2 trios in flight; completes the trio issued 3 phases back,
//   exactly when its LDS half is next read. Phase staging assignment:
//     P1 reads b0.k0, stages b1.k1<-t1 ; P2 reads b0.k1, stages b0.k0<-t0+2
//     P3 reads b1.k0, stages b0.k1<-t0+2 ; P4 reads b1.k1, stages b1.k0<-t1+2
//   Prologue = steady state shifted: stage b0.k0,b0.k1,b1.k0; vmcnt(6); barrier.
//   Tail clamps t+2 -> t (restage identical bytes, benign).
//   Grid: 768 blocks (qkv) = exactly 3 full rounds of 256 CUs; 256 (proj) = 1.
//   XCD swizzle (nwg%8==0 -> simple form bijective): chunk shares B-panels in L2.
// ============================================================================

#define STG(buf, kh, t) do { const int ko = (t) * 64 + (kh) * 32;            \
        gl_lds16(gA0 + ko, &lA[buf][kh][wave * 512]);                        \
        gl_lds16(gA1 + ko, &lA[buf][kh][4096 + wave * 512]);                 \
        gl_lds16(gB0 + ko, &lB[buf][kh][wave * 512]); } while (0)
#define LDAB(buf, kk) do { _Pragma("unroll")                                 \
        for (int i = 0; i < 4; ++i)                                          \
            af[i] = *(const short8*)&lA[buf][kk][(wm * 4 + i) * 512 + rdoff];\
        _Pragma("unroll")                                                    \
        for (int j = 0; j < 4; ++j)                                          \
            bf[j] = *(const short8*)&lB[buf][kk][(wn * 4 + j) * 512 + rdoff]; } while (0)
#define MM() do { __builtin_amdgcn_s_setprio(1); _Pragma("unroll")           \
        for (int i = 0; i < 4; ++i) { _Pragma("unroll")                      \
            for (int j = 0; j < 4; ++j)                                      \
                acc[i][j] = __builtin_amdgcn_mfma_f32_16x16x32_bf16(         \
                    af[i], bf[j], acc[i][j], 0, 0, 0); }                     \
        __builtin_amdgcn_s_setprio(0); } while (0)
#define BARX() do { asm volatile("" ::: "memory");                           \
        __builtin_amdgcn_s_barrier();                                        \
        asm volatile("" ::: "memory"); } while (0)
#define VM6() asm volatile("s_waitcnt vmcnt(6)" ::: "memory")

#define GEMM_BODY                                                            \
    const int K = CC;                                                        \
    __shared__ u16 lA[2][2][8192];                                           \
    __shared__ u16 lB[2][2][4096];                                           \
    const int tid = threadIdx.x;                                             \
    const int wave = tid >> 6, lane = tid & 63;                              \
    const int wm = wave >> 1, wn = wave & 1;                                 \
    const int quad = lane >> 4, l15 = lane & 15;                             \
    const int r0 = wave * 16 + (lane >> 2);                                  \
    const int r1 = r0 + 128;                                                 \
    const int c0 = (lane & 3) ^ ((r0 >> 1) & 3);                             \
    const u16* gA0 = Amat + (size_t)(bM + r0) * K + c0 * 8;                  \
    const u16* gA1 = Amat + (size_t)(bM + r1) * K + c0 * 8;                  \
    const u16* gB0 = Bw + (size_t)(bN + r0) * K + c0 * 8;                    \
    const int rdoff = l15 * 32 + ((quad ^ ((l15 >> 1) & 3)) * 8);            \
    floatx4 acc[4][4] = {};                                                  \
    STG(0, 0, 0); STG(0, 1, 0); STG(1, 0, 1);                                \
    VM6(); BARX();                                                           \
    for (int ii = 0; ii < 8; ++ii) {                                         \
        const int t0 = 2 * ii, t1 = t0 + 1;                                  \
        const int t2 = (t0 + 2 < 16) ? t0 + 2 : t0;                          \
        const int t3 = (t1 + 2 < 16) ? t1 + 2 : t1;                          \
        short8 af[4], bf[4];                                                 \
        LDAB(0, 0); STG(1, 1, t1); VM6(); BARX(); MM(); BARX();              \
        LDAB(0, 1); STG(0, 0, t2); VM6(); BARX(); MM(); BARX();              \
        LDAB(1, 0); STG(0, 1, t2); VM6(); BARX(); MM(); BARX();              \
        LDAB(1, 1); STG(1, 0, t3); VM6(); BARX(); MM(); BARX();              \
    }

// ---- QKV: C = xb @ qkv_w^T (+bias), scatter into Q/K/V [B*H, T, D] bf16 ----
__global__ __launch_bounds__(512, 2) void gemm_qkv(
    const u16* __restrict__ Amat, const u16* __restrict__ Bw,
    const float* __restrict__ bias,
    u16* __restrict__ Qb, u16* __restrict__ Kb, u16* __restrict__ Vb)
{
    // 768 workgroups: XCD chunk = 96 consecutive swz = 3 B-panels x 32 M-tiles
    const int raw = blockIdx.x;
    const int swz = (raw & 7) * 96 + (raw >> 3);
    const int bN = (swz >> 5) * 128;   // n-tile 0..23
    const int bM = (swz & 31) * 256;   // m-tile 0..31

    GEMM_BODY

    // epilogue: +bias, bf16, QKV scatter
#pragma unroll
    for (int mf = 0; mf < 4; ++mf)
#pragma unroll
        for (int nf = 0; nf < 4; ++nf) {
            int col = bN + wn * 64 + nf * 16 + l15;          // 0..3071
            float bv = bias[col];
            int which = col >> 10, rem = col & 1023;
            int h = rem >> 6, d = rem & 63;
            u16* dst = which == 0 ? Qb : (which == 1 ? Kb : Vb);
#pragma unroll
            for (int rg = 0; rg < 4; ++rg) {
                int row = bM + wm * 64 + mf * 16 + quad * 4 + rg;  // 0..8191
                int b = row >> 11, t = row & 2047;
                float v = acc[mf][nf][rg] + bv;
                dst[(((size_t)(b * HH + h)) * TT + t) * DD + d] = f2bf(v);
            }
        }
}

// ---- proj: Out = Yb @ proj_w^T + bias (fp32 out) ----
__global__ __launch_bounds__(512, 2) void gemm_proj(
    const u16* __restrict__ Amat, const u16* __restrict__ Bw,
    const float* __restrict__ bias, float* __restrict__ Out)
{
    // 256 workgroups: XCD chunk = 32 swz = 1 B-panel x all 32 M-tiles
    const int raw = blockIdx.x;
    const int swz = (raw & 7) * 32 + (raw >> 3);
    const int bN = (swz >> 5) * 128;   // n-tile 0..7
    const int bM = (swz & 31) * 256;   // m-tile 0..31

    GEMM_BODY

    // epilogue: +bias, fp32 out
#pragma unroll
    for (int mf = 0; mf < 4; ++mf)
#pragma unroll
        for (int nf = 0; nf < 4; ++nf) {
            int col = bN + wn * 64 + nf * 16 + l15;
            float bv = bias[col];
#pragma unroll
            for (int rg = 0; rg < 4; ++rg) {
                int row = bM + wm * 64 + mf * 16 + quad * 4 + rg;
                Out[(size_t)row * CC + col] = acc[mf][nf][rg] + bv;
            }
        }
}

#undef STG
#undef LDAB
#undef MM
#undef BARX
#undef VM6
#undef GEMM_BODY

// ---------------- flash attention, MFMA (bf16 in, fp32 acc) ------------------
// Q/K/V: [B*H, T, D] bf16.  Y: [B, T, C] bf16 (transposed for proj GEMM)
// Block: 256 threads = 4 waves; 64 queries/block (16/wave); key chunks of 64.
__global__ __launch_bounds__(256) void attn_mfma(
    const u16* __restrict__ Qb, const u16* __restrict__ Kb, const u16* __restrict__ Vb,
    u16* __restrict__ Y)
{
    __shared__ u16 Ks[64][72];        // K chunk, [j][d], +8 pad
    __shared__ u16 Vt[64][72];        // V chunk transposed [d][j], XOR-swizzled j-blocks
    __shared__ u16 Ps[4][16][72];     // per-wave P round-trip buffer [q][j]

    const int tid = threadIdx.x;
    const int wave = tid >> 6, lane = tid & 63;
    const int quad = lane >> 4, l15 = lane & 15;
    const int q0 = blockIdx.x * 64;
    const int bh = blockIdx.y;
    const int b = bh >> 4, h = bh & 15;
    const u16* Qp = Qb + (size_t)bh * TT * DD;
    const u16* Kp = Kb + (size_t)bh * TT * DD;
    const u16* Vp = Vb + (size_t)bh * TT * DD;
    const int qw = q0 + wave * 16;    // this wave's first query

    // Q A-fragments: m=l15 (query), k=quad*8+j (d), 2 k-steps
    short8 qf[2];
    qf[0] = *(const short8*)&Qp[(size_t)(qw + l15) * DD + quad * 8];
    qf[1] = *(const short8*)&Qp[(size_t)(qw + l15) * DD + 32 + quad * 8];

    float m_i[4] = { -1e30f, -1e30f, -1e30f, -1e30f };
    float l_i[4] = { 0.f, 0.f, 0.f, 0.f };
    floatx4 Oacc[4] = {};             // [dtile]; C layout: row=quad*4+reg, col(d)=dt*16+l15

    const int kb = (q0 >= WIN) ? (q0 - WIN) : 0;
    for (int j0 = kb; j0 < q0 + 64; j0 += 64) {
        __syncthreads();
        // stage K chunk [j][d], vectorized
#pragma unroll
        for (int it = 0; it < 2; ++it) {
            int slot = tid + it * 256;
            int j = slot >> 3, c8 = (slot & 7) << 3;
            *(uint4*)&Ks[j][c8] = *(const uint4*)&Kp[(size_t)(j0 + j) * DD + c8];
        }
        // stage V transposed [d][j], swizzle j-block by d>>3 (conflict-free writes)
#pragma unroll
        for (int it = 0; it < 2; ++it) {
            int slot = tid + it * 256;
            int j = slot >> 3, d0 = (slot & 7) << 3;
            uint4 raw = *(const uint4*)&Vp[(size_t)(j0 + j) * DD + d0];
            const u16* u = (const u16*)&raw;
#pragma unroll
            for (int i = 0; i < 8; ++i) {
                int d = d0 + i;
                int col = (((j >> 3) ^ (d >> 3)) << 3) + (j & 7);
                Vt[d][col] = u[i];
            }
        }
        __syncthreads();

        // ---- S = Q K^T (scaled), 4 n-tiles of 16 keys ----
        floatx4 Sacc[4] = {};
#pragma unroll
        for (int nt = 0; nt < 4; ++nt) {
            short8 kf0 = *(const short8*)&Ks[nt * 16 + l15][quad * 8];
            short8 kf1 = *(const short8*)&Ks[nt * 16 + l15][32 + quad * 8];
            Sacc[nt] = __builtin_amdgcn_mfma_f32_16x16x32_bf16(qf[0], kf0, Sacc[nt], 0, 0, 0);
            Sacc[nt] = __builtin_amdgcn_mfma_f32_16x16x32_bf16(qf[1], kf1, Sacc[nt], 0, 0, 0);
        }

        // ---- mask + scale + chunk row-max ----
        float mc[4] = { -1e30f, -1e30f, -1e30f, -1e30f };
#pragma unroll
        for (int nt = 0; nt < 4; ++nt)
#pragma unroll
            for (int r = 0; r < 4; ++r) {
                int q = qw + quad * 4 + r;
                int j = j0 + nt * 16 + l15;
                float s = (j <= q && (q - j) < WIN) ? Sacc[nt][r] * 0.125f : -1e30f;
                Sacc[nt][r] = s;
                mc[r] = fmaxf(mc[r], s);
            }
#pragma unroll
        for (int m = 1; m < 16; m <<= 1)
#pragma unroll
            for (int r = 0; r < 4; ++r) mc[r] = fmaxf(mc[r], __shfl_xor(mc[r], m, 64));

        // ---- online softmax update ----
        float alpha[4];
#pragma unroll
        for (int r = 0; r < 4; ++r) {
            float mn = fmaxf(m_i[r], mc[r]);
            alpha[r] = __expf(m_i[r] - mn);
            m_i[r] = mn;
        }
        float rs[4] = { 0.f, 0.f, 0.f, 0.f };
#pragma unroll
        for (int nt = 0; nt < 4; ++nt)
#pragma unroll
            for (int r = 0; r < 4; ++r) {
                float s = Sacc[nt][r];
                float p = (s > -1e29f) ? __expf(s - m_i[r]) : 0.f;
                Sacc[nt][r] = p;
                rs[r] += p;
            }
#pragma unroll
        for (int m = 1; m < 16; m <<= 1)
#pragma unroll
            for (int r = 0; r < 4; ++r) rs[r] += __shfl_xor(rs[r], m, 64);
#pragma unroll
        for (int r = 0; r < 4; ++r) l_i[r] = l_i[r] * alpha[r] + rs[r];
#pragma unroll
        for (int dt = 0; dt < 4; ++dt)
#pragma unroll
            for (int r = 0; r < 4; ++r) Oacc[dt][r] *= alpha[r];

        // ---- P (C layout) -> LDS -> A layout; per-wave, no barrier needed ----
#pragma unroll
        for (int nt = 0; nt < 4; ++nt)
#pragma unroll
            for (int r = 0; r < 4; ++r)
                Ps[wave][quad * 4 + r][nt * 16 + l15] = f2bf(Sacc[nt][r]);

        // ---- O += P V ----
#pragma unroll
        for (int ks = 0; ks < 2; ++ks) {
            short8 pf = *(const short8*)&Ps[wave][l15][ks * 32 + quad * 8];
#pragma unroll
            for (int dt = 0; dt < 4; ++dt) {
                int d = dt * 16 + l15;
                int col = (((ks * 4 + quad) ^ (d >> 3)) << 3);
                short8 vf = *(const short8*)&Vt[d][col];
                Oacc[dt] = __builtin_amdgcn_mfma_f32_16x16x32_bf16(pf, vf, Oacc[dt], 0, 0, 0);
            }
        }
    }

    // ---- epilogue: O / l, write Y[b,t,h*64+d] ----
    float inv[4];
#pragma unroll
    for (int r = 0; r < 4; ++r) inv[r] = 1.f / l_i[r];
#pragma unroll
    for (int dt = 0; dt < 4; ++dt)
#pragma unroll
        for (int r = 0; r < 4; ++r) {
            int t = qw + quad * 4 + r;
            int d = dt * 16 + l15;
            Y[((size_t)b * TT + t) * CC + h * DD + d] = f2bf(Oacc[dt][r] * inv[r]);
        }
}

// ---------------- launch ----------------
extern "C" void kernel_launch(void* const* d_in, const int* in_sizes, int n_in,
                              void* d_out, int out_size, void* d_ws, size_t ws_size,
                              hipStream_t stream) {
    const float* x      = (const float*)d_in[0];
    // d_in[1] = attn_mask (bool) — mask structure is analytic, unused
    const float* qkv_w  = (const float*)d_in[2];
    const float* qkv_b  = (const float*)d_in[3];
    const float* proj_w = (const float*)d_in[4];
    const float* proj_b = (const float*)d_in[5];
    float* out = (float*)d_out;

    u16* xb  = (u16*)d_ws;                         // 8192*1024
    u16* wb  = xb  + (size_t)8192 * 1024;          // 3072*1024
    u16* pwb = wb  + (size_t)3072 * 1024;          // 1024*1024
    u16* Qb  = pwb + (size_t)1024 * 1024;          // 64*2048*64
    u16* Kb  = Qb  + (size_t)64 * 2048 * 64;
    u16* Vb  = Kb  + (size_t)64 * 2048 * 64;
    u16* Yb  = Vb  + (size_t)64 * 2048 * 64;       // 8192*1024

    cvt_all<<<6144, 256, 0, stream>>>(x, qkv_w, proj_w, xb, wb, pwb);
    gemm_qkv<<<768, 512, 0, stream>>>(xb, wb, qkv_b, Qb, Kb, Vb);
    attn_mfma<<<dim3(TT / 64, BB * HH), 256, 0, stream>>>(Qb, Kb, Vb, Yb);
    gemm_proj<<<256, 512, 0, stream>>>(Yb, pwb, proj_b, out);
}

// Round 4
// 243.171 us; speedup vs baseline: 1.0824x; 1.0824x over previous
//
#include <hip/hip_runtime.h>

#define BB 4
#define TT 2048
#define CC 1024
#define HH 16
#define DD 64
#define WIN 256

typedef __attribute__((ext_vector_type(8))) short short8;
typedef __attribute__((ext_vector_type(4))) float floatx4;
typedef unsigned short u16;

typedef __attribute__((address_space(3))) void lds_void;
typedef const __attribute__((address_space(1))) void g_void;

__device__ __forceinline__ void gl_lds16(const u16* g, u16* l) {
    // async DMA global->LDS, 16B/lane; LDS dst = wave-uniform base + lane*16
    __builtin_amdgcn_global_load_lds((g_void*)g, (lds_void*)l, 16, 0, 0);
}

__device__ __forceinline__ float bf2f(u16 u) {
    union { unsigned int i; float f; } v; v.i = ((unsigned int)u) << 16; return v.f;
}
__device__ __forceinline__ u16 f2bf(float f) {
    union { float f; unsigned int i; } v; v.f = f;
    unsigned int x = v.i;
    x += ((x >> 16) & 1u) + 0x7FFFu;   // round-to-nearest-even
    return (u16)(x >> 16);
}

// ---------------- fp32 -> bf16 conversion (all three arrays, one launch) -----
__global__ void cvt_all(const float* __restrict__ x, const float* __restrict__ qw,
                        const float* __restrict__ pw,
                        u16* __restrict__ xb, u16* __restrict__ wb, u16* __restrict__ pwb) {
    int bid = blockIdx.x;
    const float* src; u16* dst; int off;
    if (bid < 4096)      { src = x;  dst = xb;  off = bid; }
    else if (bid < 5632) { src = qw; dst = wb;  off = bid - 4096; }
    else                 { src = pw; dst = pwb; off = bid - 5632; }
    int i = (off * 256 + (int)threadIdx.x) * 8;
    float4 a = *(const float4*)(src + i);
    float4 b = *(const float4*)(src + i + 4);
    u16 o[8] = { f2bf(a.x), f2bf(a.y), f2bf(a.z), f2bf(a.w),
                 f2bf(b.x), f2bf(b.y), f2bf(b.z), f2bf(b.w) };
    *(uint4*)(dst + i) = *(const uint4*)o;
}

// ============================================================================
// 256x128-tile bf16 GEMM, 6-slot ring pipeline (slot = 32-wide k-chunk).
//   512 threads = 8 waves (4M x 2N); per-wave output 64x64 (acc 4x4).
//   LDS 144KB: lA[6][8192] (A chunk 256r x 32c, 16KB), lB[6][4096] (128r x 32c).
//   Slot segment geometry (16r x 32c, 1KB; chunk (row,c) at within-seg
//   (row&15)*64B + (c ^ ((row>>1)&3))*16B) identical to the measured-0-conflict
//   predecessor; DMA lane->global mapping inverts the swizzle.
//   Phase P: { LDAB(slot P%6); STG(slot (P+5)%6 <- chunk P+5); vmcnt(12);
//              barrier; setprio1; 16 MFMA; setprio0; barrier }.
//   Ledger: 5 trios (15 loads) in flight; vmcnt(12) at phase P completes trio
//   for chunk P+1 exactly one phase before its read. Prefetch slack = 4 phases
//   (~1800 cyc) >= HBM latency. Tail (P>=27) restages chunk P-1 into its own
//   slot (identical bytes, benign, keeps ledger uniform). Fully unrolled.
//   XCD swizzle (M-partitioned): XCD x owns m-tiles 4x..4x+3 (A slice 2MB,
//   L2-resident) x all n-tiles; resident round = 4m x 8n -> 4MB working set.
//   A fetched ~once per chip, B ~once per XCD.
// ============================================================================

#define STG(s, t) do { const int ko = (t) * 32;                              \
        gl_lds16(gA0 + ko, &lA[s][wave * 512]);                              \
        gl_lds16(gA1 + ko, &lA[s][4096 + wave * 512]);                       \
        gl_lds16(gB0 + ko, &lB[s][wave * 512]); } while (0)
#define LDAB(s) do { _Pragma("unroll")                                       \
        for (int i = 0; i < 4; ++i)                                          \
            af[i] = *(const short8*)&lA[s][(wm * 4 + i) * 512 + rdoff];      \
        _Pragma("unroll")                                                    \
        for (int j = 0; j < 4; ++j)                                          \
            bf[j] = *(const short8*)&lB[s][(wn * 4 + j) * 512 + rdoff]; } while (0)
#define MM() do { __builtin_amdgcn_s_setprio(1); _Pragma("unroll")           \
        for (int i = 0; i < 4; ++i) { _Pragma("unroll")                      \
            for (int j = 0; j < 4; ++j)                                      \
                acc[i][j] = __builtin_amdgcn_mfma_f32_16x16x32_bf16(         \
                    af[i], bf[j], acc[i][j], 0, 0, 0); }                     \
        __builtin_amdgcn_s_setprio(0); } while (0)
#define BARX() do { asm volatile("" ::: "memory");                           \
        __builtin_amdgcn_s_barrier();                                        \
        asm volatile("" ::: "memory"); } while (0)
#define VM12() asm volatile("s_waitcnt vmcnt(12)" ::: "memory")

#define GEMM_BODY                                                            \
    const int K = CC;                                                        \
    __shared__ u16 lA[6][8192];                                              \
    __shared__ u16 lB[6][4096];                                              \
    const int tid = threadIdx.x;                                             \
    const int wave = tid >> 6, lane = tid & 63;                              \
    const int wm = wave >> 1, wn = wave & 1;                                 \
    const int quad = lane >> 4, l15 = lane & 15;                             \
    const int r0 = wave * 16 + (lane >> 2);                                  \
    const int r1 = r0 + 128;                                                 \
    const int c0 = (lane & 3) ^ ((r0 >> 1) & 3);                             \
    const u16* gA0 = Amat + (size_t)(bM + r0) * K + c0 * 8;                  \
    const u16* gA1 = Amat + (size_t)(bM + r1) * K + c0 * 8;                  \
    const u16* gB0 = Bw + (size_t)(bN + r0) * K + c0 * 8;                    \
    const int rdoff = l15 * 32 + ((quad ^ ((l15 >> 1) & 3)) * 8);            \
    floatx4 acc[4][4] = {};                                                  \
    STG(0, 0); STG(1, 1); STG(2, 2); STG(3, 3); STG(4, 4);                   \
    VM12(); BARX();                                                          \
    _Pragma("unroll")                                                        \
    for (int P = 0; P < 32; ++P) {                                           \
        short8 af[4], bf[4];                                                 \
        LDAB(P % 6);                                                         \
        STG((P + 5) % 6, (P + 5 < 32) ? (P + 5) : (P - 1));                  \
        VM12(); BARX(); MM(); BARX();                                        \
    }

// ---- QKV: C = xb @ qkv_w^T (+bias), scatter into Q/K/V [B*H, T, D] bf16 ----
__global__ __launch_bounds__(512, 2) void gemm_qkv(
    const u16* __restrict__ Amat, const u16* __restrict__ Bw,
    const float* __restrict__ bias,
    u16* __restrict__ Qb, u16* __restrict__ Kb, u16* __restrict__ Vb)
{
    // 768 wgs; XCD x (= raw&7) owns m-tiles 4x..4x+3, all 24 n-tiles.
    // Resident round (32 blocks/XCD) = 4m x 8n -> 2MB A + 2MB B in L2.
    const int raw = blockIdx.x;
    const int xcd = raw & 7;
    const int l   = raw >> 3;               // 0..95
    const int bM  = (xcd * 4 + (l & 3)) * 256;
    const int bN  = (l >> 2) * 128;         // n-tile 0..23

    GEMM_BODY

    // epilogue: +bias, bf16, QKV scatter
#pragma unroll
    for (int mf = 0; mf < 4; ++mf)
#pragma unroll
        for (int nf = 0; nf < 4; ++nf) {
            int col = bN + wn * 64 + nf * 16 + l15;          // 0..3071
            float bv = bias[col];
            int which = col >> 10, rem = col & 1023;
            int h = rem >> 6, d = rem & 63;
            u16* dst = which == 0 ? Qb : (which == 1 ? Kb : Vb);
#pragma unroll
            for (int rg = 0; rg < 4; ++rg) {
                int row = bM + wm * 64 + mf * 16 + quad * 4 + rg;  // 0..8191
                int b = row >> 11, t = row & 2047;
                float v = acc[mf][nf][rg] + bv;
                dst[(((size_t)(b * HH + h)) * TT + t) * DD + d] = f2bf(v);
            }
        }
}

// ---- proj: Out = Yb @ proj_w^T + bias (fp32 out) ----
__global__ __launch_bounds__(512, 2) void gemm_proj(
    const u16* __restrict__ Amat, const u16* __restrict__ Bw,
    const float* __restrict__ bias, float* __restrict__ Out)
{
    // 256 wgs = 1 full round; XCD x owns m-tiles 4x..4x+3, all 8 n-tiles.
    const int raw = blockIdx.x;
    const int xcd = raw & 7;
    const int l   = raw >> 3;               // 0..31
    const int bM  = (xcd * 4 + (l & 3)) * 256;
    const int bN  = (l >> 2) * 128;         // n-tile 0..7

    GEMM_BODY

    // epilogue: +bias, fp32 out
#pragma unroll
    for (int mf = 0; mf < 4; ++mf)
#pragma unroll
        for (int nf = 0; nf < 4; ++nf) {
            int col = bN + wn * 64 + nf * 16 + l15;
            float bv = bias[col];
#pragma unroll
            for (int rg = 0; rg < 4; ++rg) {
                int row = bM + wm * 64 + mf * 16 + quad * 4 + rg;
                Out[(size_t)row * CC + col] = acc[mf][nf][rg] + bv;
            }
        }
}

#undef STG
#undef LDAB
#undef MM
#undef BARX
#undef VM12
#undef GEMM_BODY

// ---------------- flash attention, MFMA (bf16 in, fp32 acc) ------------------
// Q/K/V: [B*H, T, D] bf16.  Y: [B, T, C] bf16 (transposed for proj GEMM)
// Block: 256 threads = 4 waves; 64 queries/block (16/wave); key chunks of 64.
__global__ __launch_bounds__(256) void attn_mfma(
    const u16* __restrict__ Qb, const u16* __restrict__ Kb, const u16* __restrict__ Vb,
    u16* __restrict__ Y)
{
    __shared__ u16 Ks[64][72];        // K chunk, [j][d], +8 pad
    __shared__ u16 Vt[64][72];        // V chunk transposed [d][j], XOR-swizzled j-blocks
    __shared__ u16 Ps[4][16][72];     // per-wave P round-trip buffer [q][j]

    const int tid = threadIdx.x;
    const int wave = tid >> 6, lane = tid & 63;
    const int quad = lane >> 4, l15 = lane & 15;
    const int q0 = blockIdx.x * 64;
    const int bh = blockIdx.y;
    const int b = bh >> 4, h = bh & 15;
    const u16* Qp = Qb + (size_t)bh * TT * DD;
    const u16* Kp = Kb + (size_t)bh * TT * DD;
    const u16* Vp = Vb + (size_t)bh * TT * DD;
    const int qw = q0 + wave * 16;    // this wave's first query

    // Q A-fragments: m=l15 (query), k=quad*8+j (d), 2 k-steps
    short8 qf[2];
    qf[0] = *(const short8*)&Qp[(size_t)(qw + l15) * DD + quad * 8];
    qf[1] = *(const short8*)&Qp[(size_t)(qw + l15) * DD + 32 + quad * 8];

    float m_i[4] = { -1e30f, -1e30f, -1e30f, -1e30f };
    float l_i[4] = { 0.f, 0.f, 0.f, 0.f };
    floatx4 Oacc[4] = {};             // [dtile]; C layout: row=quad*4+reg, col(d)=dt*16+l15

    const int kb = (q0 >= WIN) ? (q0 - WIN) : 0;
    for (int j0 = kb; j0 < q0 + 64; j0 += 64) {
        __syncthreads();
        // stage K chunk [j][d], vectorized
#pragma unroll
        for (int it = 0; it < 2; ++it) {
            int slot = tid + it * 256;
            int j = slot >> 3, c8 = (slot & 7) << 3;
            *(uint4*)&Ks[j][c8] = *(const uint4*)&Kp[(size_t)(j0 + j) * DD + c8];
        }
        // stage V transposed [d][j], swizzle j-block by d>>3 (conflict-free writes)
#pragma unroll
        for (int it = 0; it < 2; ++it) {
            int slot = tid + it * 256;
            int j = slot >> 3, d0 = (slot & 7) << 3;
            uint4 raw = *(const uint4*)&Vp[(size_t)(j0 + j) * DD + d0];
            const u16* u = (const u16*)&raw;
#pragma unroll
            for (int i = 0; i < 8; ++i) {
                int d = d0 + i;
                int col = (((j >> 3) ^ (d >> 3)) << 3) + (j & 7);
                Vt[d][col] = u[i];
            }
        }
        __syncthreads();

        // ---- S = Q K^T (scaled), 4 n-tiles of 16 keys ----
        floatx4 Sacc[4] = {};
#pragma unroll
        for (int nt = 0; nt < 4; ++nt) {
            short8 kf0 = *(const short8*)&Ks[nt * 16 + l15][quad * 8];
            short8 kf1 = *(const short8*)&Ks[nt * 16 + l15][32 + quad * 8];
            Sacc[nt] = __builtin_amdgcn_mfma_f32_16x16x32_bf16(qf[0], kf0, Sacc[nt], 0, 0, 0);
            Sacc[nt] = __builtin_amdgcn_mfma_f32_16x16x32_bf16(qf[1], kf1, Sacc[nt], 0, 0, 0);
        }

        // ---- mask + scale + chunk row-max ----
        float mc[4] = { -1e30f, -1e30f, -1e30f, -1e30f };
#pragma unroll
        for (int nt = 0; nt < 4; ++nt)
#pragma unroll
            for (int r = 0; r < 4; ++r) {
                int q = qw + quad * 4 + r;
                int j = j0 + nt * 16 + l15;
                float s = (j <= q && (q - j) < WIN) ? Sacc[nt][r] * 0.125f : -1e30f;
                Sacc[nt][r] = s;
                mc[r] = fmaxf(mc[r], s);
            }
#pragma unroll
        for (int m = 1; m < 16; m <<= 1)
#pragma unroll
            for (int r = 0; r < 4; ++r) mc[r] = fmaxf(mc[r], __shfl_xor(mc[r], m, 64));

        // ---- online softmax update ----
        float alpha[4];
#pragma unroll
        for (int r = 0; r < 4; ++r) {
            float mn = fmaxf(m_i[r], mc[r]);
            alpha[r] = __expf(m_i[r] - mn);
            m_i[r] = mn;
        }
        float rs[4] = { 0.f, 0.f, 0.f, 0.f };
#pragma unroll
        for (int nt = 0; nt < 4; ++nt)
#pragma unroll
            for (int r = 0; r < 4; ++r) {
                float s = Sacc[nt][r];
                float p = (s > -1e29f) ? __expf(s - m_i[r]) : 0.f;
                Sacc[nt][r] = p;
                rs[r] += p;
            }
#pragma unroll
        for (int m = 1; m < 16; m <<= 1)
#pragma unroll
            for (int r = 0; r < 4; ++r) rs[r] += __shfl_xor(rs[r], m, 64);
#pragma unroll
        for (int r = 0; r < 4; ++r) l_i[r] = l_i[r] * alpha[r] + rs[r];
#pragma unroll
        for (int dt = 0; dt < 4; ++dt)
#pragma unroll
            for (int r = 0; r < 4; ++r) Oacc[dt][r] *= alpha[r];

        // ---- P (C layout) -> LDS -> A layout; per-wave, no barrier needed ----
#pragma unroll
        for (int nt = 0; nt < 4; ++nt)
#pragma unroll
            for (int r = 0; r < 4; ++r)
                Ps[wave][quad * 4 + r][nt * 16 + l15] = f2bf(Sacc[nt][r]);

        // ---- O += P V ----
#pragma unroll
        for (int ks = 0; ks < 2; ++ks) {
            short8 pf = *(const short8*)&Ps[wave][l15][ks * 32 + quad * 8];
#pragma unroll
            for (int dt = 0; dt < 4; ++dt) {
                int d = dt * 16 + l15;
                int col = (((ks * 4 + quad) ^ (d >> 3)) << 3);
                short8 vf = *(const short8*)&Vt[d][col];
                Oacc[dt] = __builtin_amdgcn_mfma_f32_16x16x32_bf16(pf, vf, Oacc[dt], 0, 0, 0);
            }
        }
    }

    // ---- epilogue: O / l, write Y[b,t,h*64+d] ----
    float inv[4];
#pragma unroll
    for (int r = 0; r < 4; ++r) inv[r] = 1.f / l_i[r];
#pragma unroll
    for (int dt = 0; dt < 4; ++dt)
#pragma unroll
        for (int r = 0; r < 4; ++r) {
            int t = qw + quad * 4 + r;
            int d = dt * 16 + l15;
            Y[((size_t)b * TT + t) * CC + h * DD + d] = f2bf(Oacc[dt][r] * inv[r]);
        }
}

// ---------------- launch ----------------
extern "C" void kernel_launch(void* const* d_in, const int* in_sizes, int n_in,
                              void* d_out, int out_size, void* d_ws, size_t ws_size,
                              hipStream_t stream) {
    const float* x      = (const float*)d_in[0];
    // d_in[1] = attn_mask (bool) — mask structure is analytic, unused
    const float* qkv_w  = (const float*)d_in[2];
    const float* qkv_b  = (const float*)d_in[3];
    const float* proj_w = (const float*)d_in[4];
    const float* proj_b = (const float*)d_in[5];
    float* out = (float*)d_out;

    u16* xb  = (u16*)d_ws;                         // 8192*1024
    u16* wb  = xb  + (size_t)8192 * 1024;          // 3072*1024
    u16* pwb = wb  + (size_t)3072 * 1024;          // 1024*1024
    u16* Qb  = pwb + (size_t)1024 * 1024;          // 64*2048*64
    u16* Kb  = Qb  + (size_t)64 * 2048 * 64;
    u16* Vb  = Kb  + (size_t)64 * 2048 * 64;
    u16* Yb  = Vb  + (size_t)64 * 2048 * 64;       // 8192*1024

    cvt_all<<<6144, 256, 0, stream>>>(x, qkv_w, proj_w, xb, wb, pwb);
    gemm_qkv<<<768, 512, 0, stream>>>(xb, wb, qkv_b, Qb, Kb, Vb);
    attn_mfma<<<dim3(TT / 64, BB * HH), 256, 0, stream>>>(Qb, Kb, Vb, Yb);
    gemm_proj<<<256, 512, 0, stream>>>(Yb, pwb, proj_b, out);
}

// Round 5
// 234.886 us; speedup vs baseline: 1.1206x; 1.0353x over previous
//
#include <hip/hip_runtime.h>

#define BB 4
#define TT 2048
#define CC 1024
#define HH 16
#define DD 64
#define WIN 256

typedef __attribute__((ext_vector_type(8))) short short8;
typedef __attribute__((ext_vector_type(4))) float floatx4;
typedef unsigned short u16;

typedef __attribute__((address_space(3))) void lds_void;
typedef const __attribute__((address_space(1))) void g_void;

__device__ __forceinline__ void gl_lds16(const u16* g, u16* l) {
    // async DMA global->LDS, 16B/lane; LDS dst = wave-uniform base + lane*16
    __builtin_amdgcn_global_load_lds((g_void*)g, (lds_void*)l, 16, 0, 0);
}

__device__ __forceinline__ float bf2f(u16 u) {
    union { unsigned int i; float f; } v; v.i = ((unsigned int)u) << 16; return v.f;
}
__device__ __forceinline__ u16 f2bf(float f) {
    union { float f; unsigned int i; } v; v.f = f;
    unsigned int x = v.i;
    x += ((x >> 16) & 1u) + 0x7FFFu;   // round-to-nearest-even
    return (u16)(x >> 16);
}

// ---------------- fp32 -> bf16 conversion (all three arrays, one launch) -----
__global__ void cvt_all(const float* __restrict__ x, const float* __restrict__ qw,
                        const float* __restrict__ pw,
                        u16* __restrict__ xb, u16* __restrict__ wb, u16* __restrict__ pwb) {
    int bid = blockIdx.x;
    const float* src; u16* dst; int off;
    if (bid < 4096)      { src = x;  dst = xb;  off = bid; }
    else if (bid < 5632) { src = qw; dst = wb;  off = bid - 4096; }
    else                 { src = pw; dst = pwb; off = bid - 5632; }
    int i = (off * 256 + (int)threadIdx.x) * 8;
    float4 a = *(const float4*)(src + i);
    float4 b = *(const float4*)(src + i + 4);
    u16 o[8] = { f2bf(a.x), f2bf(a.y), f2bf(a.z), f2bf(a.w),
                 f2bf(b.x), f2bf(b.y), f2bf(b.z), f2bf(b.w) };
    *(uint4*)(dst + i) = *(const uint4*)o;
}

#define VM4()  asm volatile("s_waitcnt vmcnt(4)" ::: "memory")
#define BARX() do { asm volatile("" ::: "memory");                           \
        __builtin_amdgcn_s_barrier();                                        \
        asm volatile("" ::: "memory"); } while (0)

// ============================================================================
// 256 x (64*NR) bf16 GEMM tile, BK=64, barrier-light double-buffer schedule.
//   512 threads = 8 waves (2M x 4N); per-wave output 128 x (NR*16); acc 8xNR.
//   LDS: lA[2][2][8192] u16 (buf x khalf x 256r x 32c, 64KB),
//        lB[2][2][NR*2048] u16 (buf x khalf x NR*64 r x 32c).
//   Segment (16r x 32c, 1KB): chunk (row,c) at (row&15)*64B + (c^((row>>1)&3))*16B
//   -> conflict-free ds_read_b128 (measured 0 in all predecessors); DMA staging
//   inverts the swizzle via per-thread precomputed (row,c,kh) source pointers.
//   Per K-tile t (buf p=t&1), only 2 barriers + 1 vmcnt:
//     a: STG_A(p^1, t+1)[4]; vmcnt(4); BAR; lda(p,0); ldb(p,0); 8*NR MFMA;
//     b: STG_B(p^1, t+1)[NR];           lda(p,1); ldb(p,1); 8*NR MFMA; BAR;
//   vmcnt(4) at t.a: in-flight = B(t)[NR] + A(t+1)[4] -> waits until tile t
//   fully landed (A(t) is older, drains first). Phase b's reads were
//   guaranteed at t.a, so no wait/barrier; its ds_reads overlap phase-a MFMAs
//   in one barrier-free region. Write-after-read: buf p^1 writes are issued
//   after the tile-(t-1) end-barrier, whose lgkmcnt-ordered reads are done.
//   Tail clamps t+1 -> 15 (restages resident bytes into the dead buffer).
// ============================================================================
template<int NR>
__device__ __forceinline__ void gemm_core(
    const u16* __restrict__ Amat, const u16* __restrict__ Bw,
    int bM, int bN, u16* lA, u16* lB, floatx4 (&acc)[8][NR])
{
    const int K = CC;
    const int tid = threadIdx.x;
    const int wave = tid >> 6, lane = tid & 63;
    const int wm = wave >> 2, wn = wave & 3;        // 2M x 4N
    const int quad = lane >> 4, l15 = lane & 15;

    // staging source pointers (inverse of the LDS segment swizzle)
    const u16* gA[4]; int dA[4];
#pragma unroll
    for (int j = 0; j < 4; ++j) {
        int off = j * 8192 + tid * 16;              // byte offset in 32KB A tile
        int kh  = off >> 14;
        int o2  = off & 16383;
        int row = (o2 >> 10) * 16 + ((o2 & 1023) >> 6);
        int c   = ((o2 >> 4) & 3) ^ ((row >> 1) & 3);
        gA[j] = Amat + (size_t)(bM + row) * K + kh * 32 + c * 8;
        dA[j] = off >> 1;                           // u16 index
    }
    const u16* gB[NR]; int dB[NR];
#pragma unroll
    for (int j = 0; j < NR; ++j) {
        int off = j * 8192 + tid * 16;              // byte offset in NR*8KB B tile
        int kh  = (off >= NR * 4096) ? 1 : 0;
        int o2  = off - kh * NR * 4096;
        int row = (o2 >> 10) * 16 + ((o2 & 1023) >> 6);
        int c   = ((o2 >> 4) & 3) ^ ((row >> 1) & 3);
        gB[j] = Bw + (size_t)(bN + row) * K + kh * 32 + c * 8;
        dB[j] = off >> 1;
    }

    const int rdoff = l15 * 32 + ((quad ^ ((l15 >> 1) & 3)) * 8);

    short8 af[8], bf[NR];

    auto stgA = [&](int buf, int t) {
#pragma unroll
        for (int j = 0; j < 4; ++j)
            gl_lds16(gA[j] + t * 64, lA + buf * 16384 + dA[j]);
    };
    auto stgB = [&](int buf, int t) {
#pragma unroll
        for (int j = 0; j < NR; ++j)
            gl_lds16(gB[j] + t * 64, lB + buf * (NR * 4096) + dB[j]);
    };
    auto lda = [&](int buf, int kh) {
#pragma unroll
        for (int i = 0; i < 8; ++i)
            af[i] = *(const short8*)&lA[buf * 16384 + kh * 8192 + (wm * 8 + i) * 512 + rdoff];
    };
    auto ldb = [&](int buf, int kh) {
#pragma unroll
        for (int j = 0; j < NR; ++j)
            bf[j] = *(const short8*)&lB[buf * (NR * 4096) + kh * (NR * 2048) + (wn * NR + j) * 512 + rdoff];
    };
    auto mm = [&]() {
        __builtin_amdgcn_s_setprio(1);
#pragma unroll
        for (int i = 0; i < 8; ++i)
#pragma unroll
            for (int j = 0; j < NR; ++j)
                acc[i][j] = __builtin_amdgcn_mfma_f32_16x16x32_bf16(af[i], bf[j], acc[i][j], 0, 0, 0);
        __builtin_amdgcn_s_setprio(0);
    };

    // prologue: tile 0 into buf 0
    stgA(0, 0); stgB(0, 0);

    for (int ii = 0; ii < 8; ++ii) {
        const int t1 = 2 * ii + 1;
        const int t2 = (ii < 7) ? 2 * ii + 2 : 15;   // tail clamp (dead restage)
        // tile even (buf 0)
        stgA(1, t1); VM4(); BARX();
        lda(0, 0); ldb(0, 0); mm();
        stgB(1, t1);
        lda(0, 1); ldb(0, 1); mm();
        BARX();
        // tile odd (buf 1)
        stgA(0, t2); VM4(); BARX();
        lda(1, 0); ldb(1, 0); mm();
        stgB(0, t2);
        lda(1, 1); ldb(1, 1); mm();
        BARX();
    }
}

// ---- QKV: C = xb @ qkv_w^T (+bias), scatter into Q/K/V [B*H, T, D] bf16 ----
// Tile 256x192 (NR=3), grid 512 = exactly 2 full rounds of 256 CUs.
__global__ __launch_bounds__(512, 2) void gemm_qkv(
    const u16* __restrict__ Amat, const u16* __restrict__ Bw,
    const float* __restrict__ bias,
    u16* __restrict__ Qb, u16* __restrict__ Kb, u16* __restrict__ Vb)
{
    __shared__ u16 lA[2 * 16384];   // 64 KB
    __shared__ u16 lB[2 * 12288];   // 48 KB
    // XCD x owns m-tiles 4x..4x+3 (A slice 2MB, L2-resident), all 16 n-tiles.
    const int raw = blockIdx.x;
    const int xcd = raw & 7;
    const int l   = raw >> 3;               // 0..63
    const int bM  = (xcd * 4 + (l & 3)) * 256;
    const int bN  = (l >> 2) * 192;         // n-tile 0..15

    floatx4 acc[8][3] = {};
    gemm_core<3>(Amat, Bw, bM, bN, lA, lB, acc);

    const int tid = threadIdx.x;
    const int wave = tid >> 6, lane = tid & 63;
    const int wm = wave >> 2, wn = wave & 3;
    const int quad = lane >> 4, l15 = lane & 15;

    // epilogue: +bias, bf16, QKV scatter
#pragma unroll
    for (int mf = 0; mf < 8; ++mf)
#pragma unroll
        for (int nf = 0; nf < 3; ++nf) {
            int col = bN + wn * 48 + nf * 16 + l15;          // 0..3071
            float bv = bias[col];
            int which = col >> 10, rem = col & 1023;
            int h = rem >> 6, d = rem & 63;
            u16* dst = which == 0 ? Qb : (which == 1 ? Kb : Vb);
#pragma unroll
            for (int rg = 0; rg < 4; ++rg) {
                int row = bM + wm * 128 + mf * 16 + quad * 4 + rg;  // 0..8191
                int b = row >> 11, t = row & 2047;
                float v = acc[mf][nf][rg] + bv;
                dst[(((size_t)(b * HH + h)) * TT + t) * DD + d] = f2bf(v);
            }
        }
}

// ---- proj: Out = Yb @ proj_w^T + bias (fp32 out) ----
// Tile 256x128 (NR=2), grid 256 = exactly 1 full round.
__global__ __launch_bounds__(512, 2) void gemm_proj(
    const u16* __restrict__ Amat, const u16* __restrict__ Bw,
    const float* __restrict__ bias, float* __restrict__ Out)
{
    __shared__ u16 lA[2 * 16384];   // 64 KB
    __shared__ u16 lB[2 * 8192];    // 32 KB
    const int raw = blockIdx.x;
    const int xcd = raw & 7;
    const int l   = raw >> 3;               // 0..31
    const int bM  = (xcd * 4 + (l & 3)) * 256;
    const int bN  = (l >> 2) * 128;         // n-tile 0..7

    floatx4 acc[8][2] = {};
    gemm_core<2>(Amat, Bw, bM, bN, lA, lB, acc);

    const int tid = threadIdx.x;
    const int wave = tid >> 6, lane = tid & 63;
    const int wm = wave >> 2, wn = wave & 3;
    const int quad = lane >> 4, l15 = lane & 15;

    // epilogue: +bias, fp32 out
#pragma unroll
    for (int mf = 0; mf < 8; ++mf)
#pragma unroll
        for (int nf = 0; nf < 2; ++nf) {
            int col = bN + wn * 32 + nf * 16 + l15;
            float bv = bias[col];
#pragma unroll
            for (int rg = 0; rg < 4; ++rg) {
                int row = bM + wm * 128 + mf * 16 + quad * 4 + rg;
                Out[(size_t)row * CC + col] = acc[mf][nf][rg] + bv;
            }
        }
}

// ---------------- flash attention, MFMA (bf16 in, fp32 acc) ------------------
// Q/K/V: [B*H, T, D] bf16.  Y: [B, T, C] bf16 (transposed for proj GEMM)
// Block: 256 threads = 4 waves; 64 queries/block (16/wave); key chunks of 64.
__global__ __launch_bounds__(256) void attn_mfma(
    const u16* __restrict__ Qb, const u16* __restrict__ Kb, const u16* __restrict__ Vb,
    u16* __restrict__ Y)
{
    __shared__ u16 Ks[64][72];        // K chunk, [j][d], +8 pad
    __shared__ u16 Vt[64][72];        // V chunk transposed [d][j], XOR-swizzled j-blocks
    __shared__ u16 Ps[4][16][72];     // per-wave P round-trip buffer [q][j]

    const int tid = threadIdx.x;
    const int wave = tid >> 6, lane = tid & 63;
    const int quad = lane >> 4, l15 = lane & 15;
    const int q0 = blockIdx.x * 64;
    const int bh = blockIdx.y;
    const int b = bh >> 4, h = bh & 15;
    const u16* Qp = Qb + (size_t)bh * TT * DD;
    const u16* Kp = Kb + (size_t)bh * TT * DD;
    const u16* Vp = Vb + (size_t)bh * TT * DD;
    const int qw = q0 + wave * 16;    // this wave's first query

    // Q A-fragments: m=l15 (query), k=quad*8+j (d), 2 k-steps
    short8 qf[2];
    qf[0] = *(const short8*)&Qp[(size_t)(qw + l15) * DD + quad * 8];
    qf[1] = *(const short8*)&Qp[(size_t)(qw + l15) * DD + 32 + quad * 8];

    float m_i[4] = { -1e30f, -1e30f, -1e30f, -1e30f };
    float l_i[4] = { 0.f, 0.f, 0.f, 0.f };
    floatx4 Oacc[4] = {};             // [dtile]; C layout: row=quad*4+reg, col(d)=dt*16+l15

    const int kb = (q0 >= WIN) ? (q0 - WIN) : 0;
    for (int j0 = kb; j0 < q0 + 64; j0 += 64) {
        __syncthreads();
        // stage K chunk [j][d], vectorized
#pragma unroll
        for (int it = 0; it < 2; ++it) {
            int slot = tid + it * 256;
            int j = slot >> 3, c8 = (slot & 7) << 3;
            *(uint4*)&Ks[j][c8] = *(const uint4*)&Kp[(size_t)(j0 + j) * DD + c8];
        }
        // stage V transposed [d][j], swizzle j-block by d>>3 (conflict-free writes)
#pragma unroll
        for (int it = 0; it < 2; ++it) {
            int slot = tid + it * 256;
            int j = slot >> 3, d0 = (slot & 7) << 3;
            uint4 raw = *(const uint4*)&Vp[(size_t)(j0 + j) * DD + d0];
            const u16* u = (const u16*)&raw;
#pragma unroll
            for (int i = 0; i < 8; ++i) {
                int d = d0 + i;
                int col = (((j >> 3) ^ (d >> 3)) << 3) + (j & 7);
                Vt[d][col] = u[i];
            }
        }
        __syncthreads();

        // ---- S = Q K^T (scaled), 4 n-tiles of 16 keys ----
        floatx4 Sacc[4] = {};
#pragma unroll
        for (int nt = 0; nt < 4; ++nt) {
            short8 kf0 = *(const short8*)&Ks[nt * 16 + l15][quad * 8];
            short8 kf1 = *(const short8*)&Ks[nt * 16 + l15][32 + quad * 8];
            Sacc[nt] = __builtin_amdgcn_mfma_f32_16x16x32_bf16(qf[0], kf0, Sacc[nt], 0, 0, 0);
            Sacc[nt] = __builtin_amdgcn_mfma_f32_16x16x32_bf16(qf[1], kf1, Sacc[nt], 0, 0, 0);
        }

        // ---- mask + scale + chunk row-max ----
        float mc[4] = { -1e30f, -1e30f, -1e30f, -1e30f };
#pragma unroll
        for (int nt = 0; nt < 4; ++nt)
#pragma unroll
            for (int r = 0; r < 4; ++r) {
                int q = qw + quad * 4 + r;
                int j = j0 + nt * 16 + l15;
                float s = (j <= q && (q - j) < WIN) ? Sacc[nt][r] * 0.125f : -1e30f;
                Sacc[nt][r] = s;
                mc[r] = fmaxf(mc[r], s);
            }
#pragma unroll
        for (int m = 1; m < 16; m <<= 1)
#pragma unroll
            for (int r = 0; r < 4; ++r) mc[r] = fmaxf(mc[r], __shfl_xor(mc[r], m, 64));

        // ---- online softmax update ----
        float alpha[4];
#pragma unroll
        for (int r = 0; r < 4; ++r) {
            float mn = fmaxf(m_i[r], mc[r]);
            alpha[r] = __expf(m_i[r] - mn);
            m_i[r] = mn;
        }
        float rs[4] = { 0.f, 0.f, 0.f, 0.f };
#pragma unroll
        for (int nt = 0; nt < 4; ++nt)
#pragma unroll
            for (int r = 0; r < 4; ++r) {
                float s = Sacc[nt][r];
                float p = (s > -1e29f) ? __expf(s - m_i[r]) : 0.f;
                Sacc[nt][r] = p;
                rs[r] += p;
            }
#pragma unroll
        for (int m = 1; m < 16; m <<= 1)
#pragma unroll
            for (int r = 0; r < 4; ++r) rs[r] += __shfl_xor(rs[r], m, 64);
#pragma unroll
        for (int r = 0; r < 4; ++r) l_i[r] = l_i[r] * alpha[r] + rs[r];
#pragma unroll
        for (int dt = 0; dt < 4; ++dt)
#pragma unroll
            for (int r = 0; r < 4; ++r) Oacc[dt][r] *= alpha[r];

        // ---- P (C layout) -> LDS -> A layout; per-wave, no barrier needed ----
#pragma unroll
        for (int nt = 0; nt < 4; ++nt)
#pragma unroll
            for (int r = 0; r < 4; ++r)
                Ps[wave][quad * 4 + r][nt * 16 + l15] = f2bf(Sacc[nt][r]);

        // ---- O += P V ----
#pragma unroll
        for (int ks = 0; ks < 2; ++ks) {
            short8 pf = *(const short8*)&Ps[wave][l15][ks * 32 + quad * 8];
#pragma unroll
            for (int dt = 0; dt < 4; ++dt) {
                int d = dt * 16 + l15;
                int col = (((ks * 4 + quad) ^ (d >> 3)) << 3);
                short8 vf = *(const short8*)&Vt[d][col];
                Oacc[dt] = __builtin_amdgcn_mfma_f32_16x16x32_bf16(pf, vf, Oacc[dt], 0, 0, 0);
            }
        }
    }

    // ---- epilogue: O / l, write Y[b,t,h*64+d] ----
    float inv[4];
#pragma unroll
    for (int r = 0; r < 4; ++r) inv[r] = 1.f / l_i[r];
#pragma unroll
    for (int dt = 0; dt < 4; ++dt)
#pragma unroll
        for (int r = 0; r < 4; ++r) {
            int t = qw + quad * 4 + r;
            int d = dt * 16 + l15;
            Y[((size_t)b * TT + t) * CC + h * DD + d] = f2bf(Oacc[dt][r] * inv[r]);
        }
}

// ---------------- launch ----------------
extern "C" void kernel_launch(void* const* d_in, const int* in_sizes, int n_in,
                              void* d_out, int out_size, void* d_ws, size_t ws_size,
                              hipStream_t stream) {
    const float* x      = (const float*)d_in[0];
    // d_in[1] = attn_mask (bool) — mask structure is analytic, unused
    const float* qkv_w  = (const float*)d_in[2];
    const float* qkv_b  = (const float*)d_in[3];
    const float* proj_w = (const float*)d_in[4];
    const float* proj_b = (const float*)d_in[5];
    float* out = (float*)d_out;

    u16* xb  = (u16*)d_ws;                         // 8192*1024
    u16* wb  = xb  + (size_t)8192 * 1024;          // 3072*1024
    u16* pwb = wb  + (size_t)3072 * 1024;          // 1024*1024
    u16* Qb  = pwb + (size_t)1024 * 1024;          // 64*2048*64
    u16* Kb  = Qb  + (size_t)64 * 2048 * 64;
    u16* Vb  = Kb  + (size_t)64 * 2048 * 64;
    u16* Yb  = Vb  + (size_t)64 * 2048 * 64;       // 8192*1024

    cvt_all<<<6144, 256, 0, stream>>>(x, qkv_w, proj_w, xb, wb, pwb);
    gemm_qkv<<<512, 512, 0, stream>>>(xb, wb, qkv_b, Qb, Kb, Vb);
    attn_mfma<<<dim3(TT / 64, BB * HH), 256, 0, stream>>>(Qb, Kb, Vb, Yb);
    gemm_proj<<<256, 512, 0, stream>>>(Yb, pwb, proj_b, out);
}

// Round 6
// 230.721 us; speedup vs baseline: 1.1408x; 1.0181x over previous
//
#include <hip/hip_runtime.h>

#define BB 4
#define TT 2048
#define CC 1024
#define HH 16
#define DD 64
#define WIN 256

typedef __attribute__((ext_vector_type(8))) short short8;
typedef __attribute__((ext_vector_type(4))) float floatx4;
typedef unsigned short u16;

typedef __attribute__((address_space(3))) void lds_void;
typedef const __attribute__((address_space(1))) void g_void;

__device__ __forceinline__ void gl_lds16(const u16* g, u16* l) {
    // async DMA global->LDS, 16B/lane; LDS dst = wave-uniform base + lane*16
    __builtin_amdgcn_global_load_lds((g_void*)g, (lds_void*)l, 16, 0, 0);
}

__device__ __forceinline__ float bf2f(u16 u) {
    union { unsigned int i; float f; } v; v.i = ((unsigned int)u) << 16; return v.f;
}
__device__ __forceinline__ u16 f2bf(float f) {
    union { float f; unsigned int i; } v; v.f = f;
    unsigned int x = v.i;
    x += ((x >> 16) & 1u) + 0x7FFFu;   // round-to-nearest-even
    return (u16)(x >> 16);
}

// ---------------- fp32 -> bf16 conversion (all three arrays, one launch) -----
__global__ void cvt_all(const float* __restrict__ x, const float* __restrict__ qw,
                        const float* __restrict__ pw,
                        u16* __restrict__ xb, u16* __restrict__ wb, u16* __restrict__ pwb) {
    int bid = blockIdx.x;
    const float* src; u16* dst; int off;
    if (bid < 4096)      { src = x;  dst = xb;  off = bid; }
    else if (bid < 5632) { src = qw; dst = wb;  off = bid - 4096; }
    else                 { src = pw; dst = pwb; off = bid - 5632; }
    int i = (off * 256 + (int)threadIdx.x) * 8;
    float4 a = *(const float4*)(src + i);
    float4 b = *(const float4*)(src + i + 4);
    u16 o[8] = { f2bf(a.x), f2bf(a.y), f2bf(a.z), f2bf(a.w),
                 f2bf(b.x), f2bf(b.y), f2bf(b.z), f2bf(b.w) };
    *(uint4*)(dst + i) = *(const uint4*)o;
}

#define VM2()  asm volatile("s_waitcnt vmcnt(2)" ::: "memory")
#define BARX() do { asm volatile("" ::: "memory");                           \
        __builtin_amdgcn_s_barrier();                                        \
        asm volatile("" ::: "memory"); } while (0)

// ============================================================================
// 128 x (64*NR) bf16 GEMM tile, BK=64, R5's barrier-light double-buffer ledger,
// resized for 2 BLOCKS/CU (the m97 TLP mechanism: co-resident block fills the
// barrier/vmcnt envelope that lockstep waves can't).
//   512 threads = 8 waves (2M x 4N); per-wave output 64 x (NR*16); acc 4xNR.
//   LDS (qkv NR=3): lA 2x16KB + lB 2x24KB = 80KB -> exactly 2 blocks/CU.
//   Segment (16r x 32c, 1KB): chunk (row,c) at (row&15)*64B + (c^((row>>1)&3))*16B
//   -> conflict-free ds_read_b128 (measured 0 across all predecessors); DMA
//   staging inverts the swizzle via precomputed per-thread source pointers.
//   Per K-tile t (buf p=t&1), 2 barriers + 1 counted vmcnt:
//     stgA(p^1,t+1)[2]; vmcnt(2); BAR; lda(p,0); ldb(p,0); mm;
//     stgB(p^1,t+1)[NR];           lda(p,1); ldb(p,1); mm; BAR;
//   At VM2: in-flight = [A(t) rem, B(t)[NR], A(t+1)[2]]; keeping the 2 newest
//   (= A(t+1)) completes tile t exactly. Tail clamps t+1 -> 15 (dead restage).
//   WAR safe: buf p^1 writes issue only after tile t-1's end-barrier.
// ============================================================================
template<int NR>
__device__ __forceinline__ void gemm_core(
    const u16* __restrict__ Amat, const u16* __restrict__ Bw,
    int bM, int bN, u16* lA, u16* lB, floatx4 (&acc)[4][NR])
{
    const int K = CC;
    const int tid = threadIdx.x;
    const int wave = tid >> 6, lane = tid & 63;
    const int wm = wave >> 2, wn = wave & 3;        // 2M x 4N
    const int quad = lane >> 4, l15 = lane & 15;

    // staging source pointers (inverse of the LDS segment swizzle)
    const u16* gA[2]; int dA[2];
#pragma unroll
    for (int j = 0; j < 2; ++j) {
        int off = j * 8192 + tid * 16;              // byte offset in 16KB A tile
        int kh  = off >> 13;                        // half = 128r x 32c = 8KB
        int o2  = off & 8191;
        int row = (o2 >> 10) * 16 + ((o2 & 1023) >> 6);
        int c   = ((o2 >> 4) & 3) ^ ((row >> 1) & 3);
        gA[j] = Amat + (size_t)(bM + row) * K + kh * 32 + c * 8;
        dA[j] = off >> 1;                           // u16 index
    }
    const u16* gB[NR]; int dB[NR];
#pragma unroll
    for (int j = 0; j < NR; ++j) {
        int off = j * 8192 + tid * 16;              // byte offset in NR*8KB B tile
        int kh  = (off >= NR * 4096) ? 1 : 0;       // half = NR*64 r x 32c
        int o2  = off - kh * NR * 4096;
        int row = (o2 >> 10) * 16 + ((o2 & 1023) >> 6);
        int c   = ((o2 >> 4) & 3) ^ ((row >> 1) & 3);
        gB[j] = Bw + (size_t)(bN + row) * K + kh * 32 + c * 8;
        dB[j] = off >> 1;
    }

    const int rdoff = l15 * 32 + ((quad ^ ((l15 >> 1) & 3)) * 8);

    short8 af[4], bf[NR];

    auto stgA = [&](int buf, int t) {
#pragma unroll
        for (int j = 0; j < 2; ++j)
            gl_lds16(gA[j] + t * 64, lA + buf * 8192 + dA[j]);
    };
    auto stgB = [&](int buf, int t) {
#pragma unroll
        for (int j = 0; j < NR; ++j)
            gl_lds16(gB[j] + t * 64, lB + buf * (NR * 4096) + dB[j]);
    };
    auto lda = [&](int buf, int kh) {
#pragma unroll
        for (int i = 0; i < 4; ++i)
            af[i] = *(const short8*)&lA[buf * 8192 + kh * 4096 + (wm * 4 + i) * 512 + rdoff];
    };
    auto ldb = [&](int buf, int kh) {
#pragma unroll
        for (int j = 0; j < NR; ++j)
            bf[j] = *(const short8*)&lB[buf * (NR * 4096) + kh * (NR * 2048) + (wn * NR + j) * 512 + rdoff];
    };
    auto mm = [&]() {
        __builtin_amdgcn_s_setprio(1);
#pragma unroll
        for (int i = 0; i < 4; ++i)
#pragma unroll
            for (int j = 0; j < NR; ++j)
                acc[i][j] = __builtin_amdgcn_mfma_f32_16x16x32_bf16(af[i], bf[j], acc[i][j], 0, 0, 0);
        __builtin_amdgcn_s_setprio(0);
    };

    // prologue: tile 0 into buf 0
    stgA(0, 0); stgB(0, 0);

    for (int ii = 0; ii < 8; ++ii) {
        const int t1 = 2 * ii + 1;
        const int t2 = (ii < 7) ? 2 * ii + 2 : 15;   // tail clamp (dead restage)
        // tile even (buf 0)
        stgA(1, t1); VM2(); BARX();
        lda(0, 0); ldb(0, 0); mm();
        stgB(1, t1);
        lda(0, 1); ldb(0, 1); mm();
        BARX();
        // tile odd (buf 1)
        stgA(0, t2); VM2(); BARX();
        lda(1, 0); ldb(1, 0); mm();
        stgB(0, t2);
        lda(1, 1); ldb(1, 1); mm();
        BARX();
    }
}

// ---- QKV: C = xb @ qkv_w^T (+bias), scatter into Q/K/V [B*H, T, D] bf16 ----
// Tile 128x192 (NR=3), 80KB LDS -> 2 blocks/CU; grid 1024 = 2 rounds of 512.
__global__ __launch_bounds__(512, 4) void gemm_qkv(
    const u16* __restrict__ Amat, const u16* __restrict__ Bw,
    const float* __restrict__ bias,
    u16* __restrict__ Qb, u16* __restrict__ Kb, u16* __restrict__ Vb)
{
    __shared__ u16 lA[2 * 8192];    // 32 KB
    __shared__ u16 lB[2 * 12288];   // 48 KB
    // XCD x owns m-tiles 8x..8x+7 (A slice 1MB, L2-resident), all 16 n-tiles.
    const int raw = blockIdx.x;
    const int xcd = raw & 7;
    const int l   = raw >> 3;               // 0..127
    const int bM  = (xcd * 8 + (l & 7)) * 128;
    const int bN  = (l >> 3) * 192;         // n-tile 0..15

    floatx4 acc[4][3] = {};
    gemm_core<3>(Amat, Bw, bM, bN, lA, lB, acc);

    const int tid = threadIdx.x;
    const int wave = tid >> 6, lane = tid & 63;
    const int wm = wave >> 2, wn = wave & 3;
    const int quad = lane >> 4, l15 = lane & 15;

    // epilogue: +bias, bf16, QKV scatter
#pragma unroll
    for (int mf = 0; mf < 4; ++mf)
#pragma unroll
        for (int nf = 0; nf < 3; ++nf) {
            int col = bN + wn * 48 + nf * 16 + l15;          // 0..3071
            float bv = bias[col];
            int which = col >> 10, rem = col & 1023;
            int h = rem >> 6, d = rem & 63;
            u16* dst = which == 0 ? Qb : (which == 1 ? Kb : Vb);
#pragma unroll
            for (int rg = 0; rg < 4; ++rg) {
                int row = bM + wm * 64 + mf * 16 + quad * 4 + rg;  // 0..8191
                int b = row >> 11, t = row & 2047;
                float v = acc[mf][nf][rg] + bv;
                dst[(((size_t)(b * HH + h)) * TT + t) * DD + d] = f2bf(v);
            }
        }
}

// ---- proj: Out = Yb @ proj_w^T + bias (fp32 out) ----
// Tile 128x128 (NR=2), 64KB LDS -> 2 blocks/CU; grid 512 = 1 round of 512.
__global__ __launch_bounds__(512, 4) void gemm_proj(
    const u16* __restrict__ Amat, const u16* __restrict__ Bw,
    const float* __restrict__ bias, float* __restrict__ Out)
{
    __shared__ u16 lA[2 * 8192];    // 32 KB
    __shared__ u16 lB[2 * 8192];    // 32 KB
    const int raw = blockIdx.x;
    const int xcd = raw & 7;
    const int l   = raw >> 3;               // 0..63
    const int bM  = (xcd * 8 + (l & 7)) * 128;
    const int bN  = (l >> 3) * 128;         // n-tile 0..7

    floatx4 acc[4][2] = {};
    gemm_core<2>(Amat, Bw, bM, bN, lA, lB, acc);

    const int tid = threadIdx.x;
    const int wave = tid >> 6, lane = tid & 63;
    const int wm = wave >> 2, wn = wave & 3;
    const int quad = lane >> 4, l15 = lane & 15;

    // epilogue: +bias, fp32 out
#pragma unroll
    for (int mf = 0; mf < 4; ++mf)
#pragma unroll
        for (int nf = 0; nf < 2; ++nf) {
            int col = bN + wn * 32 + nf * 16 + l15;
            float bv = bias[col];
#pragma unroll
            for (int rg = 0; rg < 4; ++rg) {
                int row = bM + wm * 64 + mf * 16 + quad * 4 + rg;
                Out[(size_t)row * CC + col] = acc[mf][nf][rg] + bv;
            }
        }
}

// ---------------- flash attention, MFMA (bf16 in, fp32 acc) ------------------
// Q/K/V: [B*H, T, D] bf16.  Y: [B, T, C] bf16 (transposed for proj GEMM)
// Block: 256 threads = 4 waves; 64 queries/block (16/wave); key chunks of 64.
__global__ __launch_bounds__(256) void attn_mfma(
    const u16* __restrict__ Qb, const u16* __restrict__ Kb, const u16* __restrict__ Vb,
    u16* __restrict__ Y)
{
    __shared__ u16 Ks[64][72];        // K chunk, [j][d], +8 pad
    __shared__ u16 Vt[64][72];        // V chunk transposed [d][j], XOR-swizzled j-blocks
    __shared__ u16 Ps[4][16][72];     // per-wave P round-trip buffer [q][j]

    const int tid = threadIdx.x;
    const int wave = tid >> 6, lane = tid & 63;
    const int quad = lane >> 4, l15 = lane & 15;
    const int q0 = blockIdx.x * 64;
    const int bh = blockIdx.y;
    const int b = bh >> 4, h = bh & 15;
    const u16* Qp = Qb + (size_t)bh * TT * DD;
    const u16* Kp = Kb + (size_t)bh * TT * DD;
    const u16* Vp = Vb + (size_t)bh * TT * DD;
    const int qw = q0 + wave * 16;    // this wave's first query

    // Q A-fragments: m=l15 (query), k=quad*8+j (d), 2 k-steps
    short8 qf[2];
    qf[0] = *(const short8*)&Qp[(size_t)(qw + l15) * DD + quad * 8];
    qf[1] = *(const short8*)&Qp[(size_t)(qw + l15) * DD + 32 + quad * 8];

    float m_i[4] = { -1e30f, -1e30f, -1e30f, -1e30f };
    float l_i[4] = { 0.f, 0.f, 0.f, 0.f };
    floatx4 Oacc[4] = {};             // [dtile]; C layout: row=quad*4+reg, col(d)=dt*16+l15

    const int kb = (q0 >= WIN) ? (q0 - WIN) : 0;
    for (int j0 = kb; j0 < q0 + 64; j0 += 64) {
        __syncthreads();
        // stage K chunk [j][d], vectorized
#pragma unroll
        for (int it = 0; it < 2; ++it) {
            int slot = tid + it * 256;
            int j = slot >> 3, c8 = (slot & 7) << 3;
            *(uint4*)&Ks[j][c8] = *(const uint4*)&Kp[(size_t)(j0 + j) * DD + c8];
        }
        // stage V transposed [d][j], swizzle j-block by d>>3 (conflict-free writes)
#pragma unroll
        for (int it = 0; it < 2; ++it) {
            int slot = tid + it * 256;
            int j = slot >> 3, d0 = (slot & 7) << 3;
            uint4 raw = *(const uint4*)&Vp[(size_t)(j0 + j) * DD + d0];
            const u16* u = (const u16*)&raw;
#pragma unroll
            for (int i = 0; i < 8; ++i) {
                int d = d0 + i;
                int col = (((j >> 3) ^ (d >> 3)) << 3) + (j & 7);
                Vt[d][col] = u[i];
            }
        }
        __syncthreads();

        // ---- S = Q K^T (scaled), 4 n-tiles of 16 keys ----
        floatx4 Sacc[4] = {};
#pragma unroll
        for (int nt = 0; nt < 4; ++nt) {
            short8 kf0 = *(const short8*)&Ks[nt * 16 + l15][quad * 8];
            short8 kf1 = *(const short8*)&Ks[nt * 16 + l15][32 + quad * 8];
            Sacc[nt] = __builtin_amdgcn_mfma_f32_16x16x32_bf16(qf[0], kf0, Sacc[nt], 0, 0, 0);
            Sacc[nt] = __builtin_amdgcn_mfma_f32_16x16x32_bf16(qf[1], kf1, Sacc[nt], 0, 0, 0);
        }

        // ---- mask + scale + chunk row-max ----
        float mc[4] = { -1e30f, -1e30f, -1e30f, -1e30f };
#pragma unroll
        for (int nt = 0; nt < 4; ++nt)
#pragma unroll
            for (int r = 0; r < 4; ++r) {
                int q = qw + quad * 4 + r;
                int j = j0 + nt * 16 + l15;
                float s = (j <= q && (q - j) < WIN) ? Sacc[nt][r] * 0.125f : -1e30f;
                Sacc[nt][r] = s;
                mc[r] = fmaxf(mc[r], s);
            }
#pragma unroll
        for (int m = 1; m < 16; m <<= 1)
#pragma unroll
            for (int r = 0; r < 4; ++r) mc[r] = fmaxf(mc[r], __shfl_xor(mc[r], m, 64));

        // ---- online softmax update ----
        float alpha[4];
#pragma unroll
        for (int r = 0; r < 4; ++r) {
            float mn = fmaxf(m_i[r], mc[r]);
            alpha[r] = __expf(m_i[r] - mn);
            m_i[r] = mn;
        }
        float rs[4] = { 0.f, 0.f, 0.f, 0.f };
#pragma unroll
        for (int nt = 0; nt < 4; ++nt)
#pragma unroll
            for (int r = 0; r < 4; ++r) {
                float s = Sacc[nt][r];
                float p = (s > -1e29f) ? __expf(s - m_i[r]) : 0.f;
                Sacc[nt][r] = p;
                rs[r] += p;
            }
#pragma unroll
        for (int m = 1; m < 16; m <<= 1)
#pragma unroll
            for (int r = 0; r < 4; ++r) rs[r] += __shfl_xor(rs[r], m, 64);
#pragma unroll
        for (int r = 0; r < 4; ++r) l_i[r] = l_i[r] * alpha[r] + rs[r];
#pragma unroll
        for (int dt = 0; dt < 4; ++dt)
#pragma unroll
            for (int r = 0; r < 4; ++r) Oacc[dt][r] *= alpha[r];

        // ---- P (C layout) -> LDS -> A layout; per-wave, no barrier needed ----
#pragma unroll
        for (int nt = 0; nt < 4; ++nt)
#pragma unroll
            for (int r = 0; r < 4; ++r)
                Ps[wave][quad * 4 + r][nt * 16 + l15] = f2bf(Sacc[nt][r]);

        // ---- O += P V ----
#pragma unroll
        for (int ks = 0; ks < 2; ++ks) {
            short8 pf = *(const short8*)&Ps[wave][l15][ks * 32 + quad * 8];
#pragma unroll
            for (int dt = 0; dt < 4; ++dt) {
                int d = dt * 16 + l15;
                int col = (((ks * 4 + quad) ^ (d >> 3)) << 3);
                short8 vf = *(const short8*)&Vt[d][col];
                Oacc[dt] = __builtin_amdgcn_mfma_f32_16x16x32_bf16(pf, vf, Oacc[dt], 0, 0, 0);
            }
        }
    }

    // ---- epilogue: O / l, write Y[b,t,h*64+d] ----
    float inv[4];
#pragma unroll
    for (int r = 0; r < 4; ++r) inv[r] = 1.f / l_i[r];
#pragma unroll
    for (int dt = 0; dt < 4; ++dt)
#pragma unroll
        for (int r = 0; r < 4; ++r) {
            int t = qw + quad * 4 + r;
            int d = dt * 16 + l15;
            Y[((size_t)b * TT + t) * CC + h * DD + d] = f2bf(Oacc[dt][r] * inv[r]);
        }
}

// ---------------- launch ----------------
extern "C" void kernel_launch(void* const* d_in, const int* in_sizes, int n_in,
                              void* d_out, int out_size, void* d_ws, size_t ws_size,
                              hipStream_t stream) {
    const float* x      = (const float*)d_in[0];
    // d_in[1] = attn_mask (bool) — mask structure is analytic, unused
    const float* qkv_w  = (const float*)d_in[2];
    const float* qkv_b  = (const float*)d_in[3];
    const float* proj_w = (const float*)d_in[4];
    const float* proj_b = (const float*)d_in[5];
    float* out = (float*)d_out;

    u16* xb  = (u16*)d_ws;                         // 8192*1024
    u16* wb  = xb  + (size_t)8192 * 1024;          // 3072*1024
    u16* pwb = wb  + (size_t)3072 * 1024;          // 1024*1024
    u16* Qb  = pwb + (size_t)1024 * 1024;          // 64*2048*64
    u16* Kb  = Qb  + (size_t)64 * 2048 * 64;
    u16* Vb  = Kb  + (size_t)64 * 2048 * 64;
    u16* Yb  = Vb  + (size_t)64 * 2048 * 64;       // 8192*1024

    cvt_all<<<6144, 256, 0, stream>>>(x, qkv_w, proj_w, xb, wb, pwb);
    gemm_qkv<<<1024, 512, 0, stream>>>(xb, wb, qkv_b, Qb, Kb, Vb);
    attn_mfma<<<dim3(TT / 64, BB * HH), 256, 0, stream>>>(Qb, Kb, Vb, Yb);
    gemm_proj<<<512, 512, 0, stream>>>(Yb, pwb, proj_b, out);
}

// Round 8
// 219.577 us; speedup vs baseline: 1.1987x; 1.0508x over previous
//
#include <hip/hip_runtime.h>

#define BB 4
#define TT 2048
#define CC 1024
#define HH 16
#define DD 64
#define WIN 256

typedef __attribute__((ext_vector_type(8))) short short8;
typedef __attribute__((ext_vector_type(4))) float floatx4;
typedef unsigned short u16;

typedef __attribute__((address_space(3))) void lds_void;
typedef const __attribute__((address_space(1))) void g_void;

__device__ __forceinline__ void gl_lds16(const u16* g, u16* l) {
    // async DMA global->LDS, 16B/lane; LDS dst = wave-uniform base + lane*16
    __builtin_amdgcn_global_load_lds((g_void*)g, (lds_void*)l, 16, 0, 0);
}

__device__ __forceinline__ float bf2f(u16 u) {
    union { unsigned int i; float f; } v; v.i = ((unsigned int)u) << 16; return v.f;
}
__device__ __forceinline__ u16 f2bf(float f) {
    union { float f; unsigned int i; } v; v.f = f;
    unsigned int x = v.i;
    x += ((x >> 16) & 1u) + 0x7FFFu;   // round-to-nearest-even
    return (u16)(x >> 16);
}

// ---------------- fp32 -> bf16 conversion (all three arrays, one launch) -----
__global__ void cvt_all(const float* __restrict__ x, const float* __restrict__ qw,
                        const float* __restrict__ pw,
                        u16* __restrict__ xb, u16* __restrict__ wb, u16* __restrict__ pwb) {
    int bid = blockIdx.x;
    const float* src; u16* dst; int off;
    if (bid < 4096)      { src = x;  dst = xb;  off = bid; }
    else if (bid < 5632) { src = qw; dst = wb;  off = bid - 4096; }
    else                 { src = pw; dst = pwb; off = bid - 5632; }
    int i = (off * 256 + (int)threadIdx.x) * 8;
    float4 a = *(const float4*)(src + i);
    float4 b = *(const float4*)(src + i + 4);
    u16 o[8] = { f2bf(a.x), f2bf(a.y), f2bf(a.z), f2bf(a.w),
                 f2bf(b.x), f2bf(b.y), f2bf(b.z), f2bf(b.w) };
    *(uint4*)(dst + i) = *(const uint4*)o;
}

#define VM2()  asm volatile("s_waitcnt vmcnt(2)" ::: "memory")
#define BARX() do { asm volatile("" ::: "memory");                           \
        __builtin_amdgcn_s_barrier();                                        \
        asm volatile("" ::: "memory"); } while (0)

// ============================================================================
// 128 x (64*NR) bf16 GEMM tile, BK=64, barrier-light double-buffer ledger,
// sized for 2 blocks/CU (co-resident block fills the barrier/vmcnt envelope).
//   512 threads = 8 waves (2M x 4N); per-wave output 64 x (NR*16); acc 4xNR.
//   LDS (qkv NR=3): lA 2x16KB + lB 2x24KB = 80KB -> exactly 2 blocks/CU.
//   Segment (16r x 32c, 1KB): chunk (row,c) at (row&15)*64B + (c^((row>>1)&3))*16B
//   -> conflict-free ds_read_b128 (measured 0 across all predecessors); DMA
//   staging inverts the swizzle via precomputed per-thread source pointers.
//   Per K-tile t (buf p=t&1), 2 barriers + 1 counted vmcnt:
//     stgA(p^1,t+1)[2]; vmcnt(2); BAR; lda(p,0); ldb(p,0); mm;
//     stgB(p^1,t+1)[NR];           lda(p,1); ldb(p,1); mm; BAR;
//   At VM2: in-flight = [A(t) rem, B(t)[NR], A(t+1)[2]]; keeping the 2 newest
//   (= A(t+1)) completes tile t exactly. Tail clamps t+1 -> 15 (dead restage).
//   WAR safe: buf p^1 writes issue only after tile t-1's end-barrier.
// ============================================================================
template<int NR>
__device__ __forceinline__ void gemm_core(
    const u16* __restrict__ Amat, const u16* __restrict__ Bw,
    int bM, int bN, u16* lA, u16* lB, floatx4 (&acc)[4][NR])
{
    const int K = CC;
    const int tid = threadIdx.x;
    const int wave = tid >> 6, lane = tid & 63;
    const int wm = wave >> 2, wn = wave & 3;        // 2M x 4N
    const int quad = lane >> 4, l15 = lane & 15;

    // staging source pointers (inverse of the LDS segment swizzle)
    const u16* gA[2]; int dA[2];
#pragma unroll
    for (int j = 0; j < 2; ++j) {
        int off = j * 8192 + tid * 16;              // byte offset in 16KB A tile
        int kh  = off >> 13;                        // half = 128r x 32c = 8KB
        int o2  = off & 8191;
        int row = (o2 >> 10) * 16 + ((o2 & 1023) >> 6);
        int c   = ((o2 >> 4) & 3) ^ ((row >> 1) & 3);
        gA[j] = Amat + (size_t)(bM + row) * K + kh * 32 + c * 8;
        dA[j] = off >> 1;                           // u16 index
    }
    const u16* gB[NR]; int dB[NR];
#pragma unroll
    for (int j = 0; j < NR; ++j) {
        int off = j * 8192 + tid * 16;              // byte offset in NR*8KB B tile
        int kh  = (off >= NR * 4096) ? 1 : 0;       // half = NR*64 r x 32c
        int o2  = off - kh * NR * 4096;
        int row = (o2 >> 10) * 16 + ((o2 & 1023) >> 6);
        int c   = ((o2 >> 4) & 3) ^ ((row >> 1) & 3);
        gB[j] = Bw + (size_t)(bN + row) * K + kh * 32 + c * 8;
        dB[j] = off >> 1;
    }

    const int rdoff = l15 * 32 + ((quad ^ ((l15 >> 1) & 3)) * 8);

    short8 af[4], bf[NR];

    auto stgA = [&](int buf, int t) {
#pragma unroll
        for (int j = 0; j < 2; ++j)
            gl_lds16(gA[j] + t * 64, lA + buf * 8192 + dA[j]);
    };
    auto stgB = [&](int buf, int t) {
#pragma unroll
        for (int j = 0; j < NR; ++j)
            gl_lds16(gB[j] + t * 64, lB + buf * (NR * 4096) + dB[j]);
    };
    auto lda = [&](int buf, int kh) {
#pragma unroll
        for (int i = 0; i < 4; ++i)
            af[i] = *(const short8*)&lA[buf * 8192 + kh * 4096 + (wm * 4 + i) * 512 + rdoff];
    };
    auto ldb = [&](int buf, int kh) {
#pragma unroll
        for (int j = 0; j < NR; ++j)
            bf[j] = *(const short8*)&lB[buf * (NR * 4096) + kh * (NR * 2048) + (wn * NR + j) * 512 + rdoff];
    };
    auto mm = [&]() {
        __builtin_amdgcn_s_setprio(1);
#pragma unroll
        for (int i = 0; i < 4; ++i)
#pragma unroll
            for (int j = 0; j < NR; ++j)
                acc[i][j] = __builtin_amdgcn_mfma_f32_16x16x32_bf16(af[i], bf[j], acc[i][j], 0, 0, 0);
        __builtin_amdgcn_s_setprio(0);
    };

    // prologue: tile 0 into buf 0
    stgA(0, 0); stgB(0, 0);

    for (int ii = 0; ii < 8; ++ii) {
        const int t1 = 2 * ii + 1;
        const int t2 = (ii < 7) ? 2 * ii + 2 : 15;   // tail clamp (dead restage)
        // tile even (buf 0)
        stgA(1, t1); VM2(); BARX();
        lda(0, 0); ldb(0, 0); mm();
        stgB(1, t1);
        lda(0, 1); ldb(0, 1); mm();
        BARX();
        // tile odd (buf 1)
        stgA(0, t2); VM2(); BARX();
        lda(1, 0); ldb(1, 0); mm();
        stgB(0, t2);
        lda(1, 1); ldb(1, 1); mm();
        BARX();
    }
}

// ---- QKV: C = xb @ qkv_w^T (+bias), scatter into Q/K/V [B*H, T, D] bf16 ----
// Tile 128x192 (NR=3), 80KB LDS -> 2 blocks/CU; grid 1024 = 2 rounds of 512.
__global__ __launch_bounds__(512, 4) void gemm_qkv(
    const u16* __restrict__ Amat, const u16* __restrict__ Bw,
    const float* __restrict__ bias,
    u16* __restrict__ Qb, u16* __restrict__ Kb, u16* __restrict__ Vb)
{
    __shared__ u16 lA[2 * 8192];    // 32 KB
    __shared__ u16 lB[2 * 12288];   // 48 KB
    // XCD x owns m-tiles 8x..8x+7 (A slice 1MB, L2-resident), all 16 n-tiles.
    const int raw = blockIdx.x;
    const int xcd = raw & 7;
    const int l   = raw >> 3;               // 0..127
    const int bM  = (xcd * 8 + (l & 7)) * 128;
    const int bN  = (l >> 3) * 192;         // n-tile 0..15

    floatx4 acc[4][3] = {};
    gemm_core<3>(Amat, Bw, bM, bN, lA, lB, acc);

    const int tid = threadIdx.x;
    const int wave = tid >> 6, lane = tid & 63;
    const int wm = wave >> 2, wn = wave & 3;
    const int quad = lane >> 4, l15 = lane & 15;

    // epilogue: +bias, bf16, QKV scatter
#pragma unroll
    for (int mf = 0; mf < 4; ++mf)
#pragma unroll
        for (int nf = 0; nf < 3; ++nf) {
            int col = bN + wn * 48 + nf * 16 + l15;          // 0..3071
            float bv = bias[col];
            int which = col >> 10, rem = col & 1023;
            int h = rem >> 6, d = rem & 63;
            u16* dst = which == 0 ? Qb : (which == 1 ? Kb : Vb);
#pragma unroll
            for (int rg = 0; rg < 4; ++rg) {
                int row = bM + wm * 64 + mf * 16 + quad * 4 + rg;  // 0..8191
                int b = row >> 11, t = row & 2047;
                float v = acc[mf][nf][rg] + bv;
                dst[(((size_t)(b * HH + h)) * TT + t) * DD + d] = f2bf(v);
            }
        }
}

// ---- proj: Out = Yb @ proj_w^T + bias (fp32 out) ----
// Tile 128x128 (NR=2), 64KB LDS -> 2 blocks/CU; grid 512 = 1 round of 512.
__global__ __launch_bounds__(512, 4) void gemm_proj(
    const u16* __restrict__ Amat, const u16* __restrict__ Bw,
    const float* __restrict__ bias, float* __restrict__ Out)
{
    __shared__ u16 lA[2 * 8192];    // 32 KB
    __shared__ u16 lB[2 * 8192];    // 32 KB
    const int raw = blockIdx.x;
    const int xcd = raw & 7;
    const int l   = raw >> 3;               // 0..63
    const int bM  = (xcd * 8 + (l & 7)) * 128;
    const int bN  = (l >> 3) * 128;         // n-tile 0..7

    floatx4 acc[4][2] = {};
    gemm_core<2>(Amat, Bw, bM, bN, lA, lB, acc);

    const int tid = threadIdx.x;
    const int wave = tid >> 6, lane = tid & 63;
    const int wm = wave >> 2, wn = wave & 3;
    const int quad = lane >> 4, l15 = lane & 15;

    // epilogue: +bias, fp32 out
#pragma unroll
    for (int mf = 0; mf < 4; ++mf)
#pragma unroll
        for (int nf = 0; nf < 2; ++nf) {
            int col = bN + wn * 32 + nf * 16 + l15;
            float bv = bias[col];
#pragma unroll
            for (int rg = 0; rg < 4; ++rg) {
                int row = bM + wm * 64 + mf * 16 + quad * 4 + rg;
                Out[(size_t)row * CC + col] = acc[mf][nf][rg] + bv;
            }
        }
}

// ---------------- flash attention, MFMA (bf16 in, fp32 acc) ------------------
// Q/K/V: [B*H, T, D] bf16.  Y: [B, T, C] bf16 (transposed for proj GEMM)
// Block: 256 threads = 4 waves; 64 queries/block (16/wave); key chunks of 64.
// Grid (bh, qtile): linear id = bh + 64*qtile -> all q-tiles of a head hit the
// SAME XCD (id%8 = bh%8) -> K/V chunks L2-resident across their ~5 consumer
// q-tiles (was ~5 different XCDs -> ~5x HBM re-fetch).
__global__ __launch_bounds__(256) void attn_mfma(
    const u16* __restrict__ Qb, const u16* __restrict__ Kb, const u16* __restrict__ Vb,
    u16* __restrict__ Y)
{
    __shared__ u16 Ks[64][72];        // K chunk, [j][d], +8 pad
    __shared__ u16 Vt[64][72];        // V chunk transposed [d][j], XOR-swizzled j-blocks
    __shared__ u16 Ps[4][16][72];     // per-wave P round-trip buffer [q][j]

    const int tid = threadIdx.x;
    const int wave = tid >> 6, lane = tid & 63;
    const int quad = lane >> 4, l15 = lane & 15;
    const int q0 = blockIdx.y * 64;
    const int bh = blockIdx.x;
    const int b = bh >> 4, h = bh & 15;
    const u16* Qp = Qb + (size_t)bh * TT * DD;
    const u16* Kp = Kb + (size_t)bh * TT * DD;
    const u16* Vp = Vb + (size_t)bh * TT * DD;
    const int qw = q0 + wave * 16;    // this wave's first query

    // Q A-fragments: m=l15 (query), k=quad*8+j (d), 2 k-steps
    short8 qf[2];
    qf[0] = *(const short8*)&Qp[(size_t)(qw + l15) * DD + quad * 8];
    qf[1] = *(const short8*)&Qp[(size_t)(qw + l15) * DD + 32 + quad * 8];

    float m_i[4] = { -1e30f, -1e30f, -1e30f, -1e30f };
    float l_i[4] = { 0.f, 0.f, 0.f, 0.f };
    floatx4 Oacc[4] = {};             // [dtile]; C layout: row=quad*4+reg, col(d)=dt*16+l15

    const int kb = (q0 >= WIN) ? (q0 - WIN) : 0;
    for (int j0 = kb; j0 < q0 + 64; j0 += 64) {
        __syncthreads();
        // stage K chunk [j][d], vectorized
#pragma unroll
        for (int it = 0; it < 2; ++it) {
            int slot = tid + it * 256;
            int j = slot >> 3, c8 = (slot & 7) << 3;
            *(uint4*)&Ks[j][c8] = *(const uint4*)&Kp[(size_t)(j0 + j) * DD + c8];
        }
        // stage V transposed [d][j], swizzle j-block by d>>3 (conflict-free writes)
#pragma unroll
        for (int it = 0; it < 2; ++it) {
            int slot = tid + it * 256;
            int j = slot >> 3, d0 = (slot & 7) << 3;
            uint4 raw = *(const uint4*)&Vp[(size_t)(j0 + j) * DD + d0];
            const u16* u = (const u16*)&raw;
#pragma unroll
            for (int i = 0; i < 8; ++i) {
                int d = d0 + i;
                int col = (((j >> 3) ^ (d >> 3)) << 3) + (j & 7);
                Vt[d][col] = u[i];
            }
        }
        __syncthreads();

        // ---- S = Q K^T (scaled), 4 n-tiles of 16 keys ----
        floatx4 Sacc[4] = {};
        __builtin_amdgcn_s_setprio(1);
#pragma unroll
        for (int nt = 0; nt < 4; ++nt) {
            short8 kf0 = *(const short8*)&Ks[nt * 16 + l15][quad * 8];
            short8 kf1 = *(const short8*)&Ks[nt * 16 + l15][32 + quad * 8];
            Sacc[nt] = __builtin_amdgcn_mfma_f32_16x16x32_bf16(qf[0], kf0, Sacc[nt], 0, 0, 0);
            Sacc[nt] = __builtin_amdgcn_mfma_f32_16x16x32_bf16(qf[1], kf1, Sacc[nt], 0, 0, 0);
        }
        __builtin_amdgcn_s_setprio(0);

        // ---- mask + scale + chunk row-max ----
        float mc[4] = { -1e30f, -1e30f, -1e30f, -1e30f };
#pragma unroll
        for (int nt = 0; nt < 4; ++nt)
#pragma unroll
            for (int r = 0; r < 4; ++r) {
                int q = qw + quad * 4 + r;
                int j = j0 + nt * 16 + l15;
                float s = (j <= q && (q - j) < WIN) ? Sacc[nt][r] * 0.125f : -1e30f;
                Sacc[nt][r] = s;
                mc[r] = fmaxf(mc[r], s);
            }
#pragma unroll
        for (int m = 1; m < 16; m <<= 1)
#pragma unroll
            for (int r = 0; r < 4; ++r) mc[r] = fmaxf(mc[r], __shfl_xor(mc[r], m, 64));

        // ---- online softmax update ----
        float alpha[4];
#pragma unroll
        for (int r = 0; r < 4; ++r) {
            float mn = fmaxf(m_i[r], mc[r]);
            alpha[r] = __expf(m_i[r] - mn);
            m_i[r] = mn;
        }
        float rs[4] = { 0.f, 0.f, 0.f, 0.f };
#pragma unroll
        for (int nt = 0; nt < 4; ++nt)
#pragma unroll
            for (int r = 0; r < 4; ++r) {
                float s = Sacc[nt][r];
                float p = (s > -1e29f) ? __expf(s - m_i[r]) : 0.f;
                Sacc[nt][r] = p;
                rs[r] += p;
            }
#pragma unroll
        for (int m = 1; m < 16; m <<= 1)
#pragma unroll
            for (int r = 0; r < 4; ++r) rs[r] += __shfl_xor(rs[r], m, 64);
#pragma unroll
        for (int r = 0; r < 4; ++r) l_i[r] = l_i[r] * alpha[r] + rs[r];
#pragma unroll
        for (int dt = 0; dt < 4; ++dt)
#pragma unroll
            for (int r = 0; r < 4; ++r) Oacc[dt][r] *= alpha[r];

        // ---- P (C layout) -> LDS -> A layout; per-wave, no barrier needed ----
#pragma unroll
        for (int nt = 0; nt < 4; ++nt)
#pragma unroll
            for (int r = 0; r < 4; ++r)
                Ps[wave][quad * 4 + r][nt * 16 + l15] = f2bf(Sacc[nt][r]);

        // ---- O += P V ----
        __builtin_amdgcn_s_setprio(1);
#pragma unroll
        for (int ks = 0; ks < 2; ++ks) {
            short8 pf = *(const short8*)&Ps[wave][l15][ks * 32 + quad * 8];
#pragma unroll
            for (int dt = 0; dt < 4; ++dt) {
                int d = dt * 16 + l15;
                int col = (((ks * 4 + quad) ^ (d >> 3)) << 3);
                short8 vf = *(const short8*)&Vt[d][col];
                Oacc[dt] = __builtin_amdgcn_mfma_f32_16x16x32_bf16(pf, vf, Oacc[dt], 0, 0, 0);
            }
        }
        __builtin_amdgcn_s_setprio(0);
    }

    // ---- epilogue: O / l, write Y[b,t,h*64+d] ----
    float inv[4];
#pragma unroll
    for (int r = 0; r < 4; ++r) inv[r] = 1.f / l_i[r];
#pragma unroll
    for (int dt = 0; dt < 4; ++dt)
#pragma unroll
        for (int r = 0; r < 4; ++r) {
            int t = qw + quad * 4 + r;
            int d = dt * 16 + l15;
            Y[((size_t)b * TT + t) * CC + h * DD + d] = f2bf(Oacc[dt][r] * inv[r]);
        }
}

// ---------------- launch ----------------
extern "C" void kernel_launch(void* const* d_in, const int* in_sizes, int n_in,
                              void* d_out, int out_size, void* d_ws, size_t ws_size,
                              hipStream_t stream) {
    const float* x      = (const float*)d_in[0];
    // d_in[1] = attn_mask (bool) — mask structure is analytic, unused
    const float* qkv_w  = (const float*)d_in[2];
    const float* qkv_b  = (const float*)d_in[3];
    const float* proj_w = (const float*)d_in[4];
    const float* proj_b = (const float*)d_in[5];
    float* out = (float*)d_out;

    u16* xb  = (u16*)d_ws;                         // 8192*1024
    u16* wb  = xb  + (size_t)8192 * 1024;          // 3072*1024
    u16* pwb = wb  + (size_t)3072 * 1024;          // 1024*1024
    u16* Qb  = pwb + (size_t)1024 * 1024;          // 64*2048*64
    u16* Kb  = Qb  + (size_t)64 * 2048 * 64;
    u16* Vb  = Kb  + (size_t)64 * 2048 * 64;
    u16* Yb  = Vb  + (size_t)64 * 2048 * 64;       // 8192*1024

    cvt_all<<<6144, 256, 0, stream>>>(x, qkv_w, proj_w, xb, wb, pwb);
    gemm_qkv<<<1024, 512, 0, stream>>>(xb, wb, qkv_b, Qb, Kb, Vb);
    attn_mfma<<<dim3(BB * HH, TT / 64), 256, 0, stream>>>(Qb, Kb, Vb, Yb);
    gemm_proj<<<512, 512, 0, stream>>>(Yb, pwb, proj_b, out);
}